// Round 14
// baseline (2705.671 us; speedup 1.0000x reference)
//
#include <hip/hip_runtime.h>

#define NB 256
#define NT 1000
#define ND 64
#define NH 128
#define NBLK (NB / 2)     // 2 batch rows per block, interleaved

typedef _Float16 h2 __attribute__((ext_vector_type(2)));
typedef _Float16 f16x8 __attribute__((ext_vector_type(8)));
typedef float    f32x4 __attribute__((ext_vector_type(4)));
typedef uint     u32x4 __attribute__((ext_vector_type(4)));

static __device__ __forceinline__ uint pk(float a, float b) {
    return __builtin_bit_cast(uint, __builtin_amdgcn_cvt_pkrtz(a, b));
}
static __device__ __forceinline__ float fdot2u(uint a, uint b, float c) {
#if __has_builtin(__builtin_amdgcn_fdot2)
    return __builtin_amdgcn_fdot2(__builtin_bit_cast(h2, a),
                                  __builtin_bit_cast(h2, b), c, false);
#else
    h2 ha = __builtin_bit_cast(h2, a), hb = __builtin_bit_cast(h2, b);
    return c + (float)ha.x * (float)hb.x + (float)ha.y * (float)hb.y;
#endif
}
static __device__ __forceinline__ float f16lo(uint u) {
    return (float)__builtin_bit_cast(h2, u).x;
}
static __device__ __forceinline__ float f16hi(uint u) {
    return (float)__builtin_bit_cast(h2, u).y;
}
static __device__ __forceinline__ float sigmoid_f(float x) {
    float e = __builtin_amdgcn_exp2f(-1.4426950408889634f * x);
    return __builtin_amdgcn_rcpf(1.0f + e);
}
static __device__ __forceinline__ float tanh_f(float x) {
    float e = __builtin_amdgcn_exp2f(-2.8853900817779268f * x);
    return 2.0f * __builtin_amdgcn_rcpf(1.0f + e) - 1.0f;
}
// quad butterfly sum via DPP
static __device__ __forceinline__ float qsum(float v) {
    int a = __builtin_amdgcn_update_dpp(0, __builtin_bit_cast(int, v),
                                        0xB1, 0xF, 0xF, true);
    v += __builtin_bit_cast(float, a);
    int b = __builtin_amdgcn_update_dpp(0, __builtin_bit_cast(int, v),
                                        0x4E, 0xF, 0xF, true);
    v += __builtin_bit_cast(float, b);
    return v;
}
// load 8 consecutive f32, pack to 4 f16x2 regs
static __device__ __forceinline__ void ld8(const float* p, uint* d) {
    const float4 A = *(const float4*)p;
    const float4 B = *(const float4*)(p + 4);
    d[0] = pk(A.x, A.y); d[1] = pk(A.z, A.w);
    d[2] = pk(B.x, B.y); d[3] = pk(B.z, B.w);
}
// load 8 consecutive f32 as one MFMA A-fragment (layout verified r6/r11)
static __device__ __forceinline__ f16x8 ldWfrag(const float* p) {
    const float4 a = *(const float4*)p;
    const float4 b = *(const float4*)(p + 4);
    u32x4 u = { pk(a.x, a.y), pk(a.z, a.w), pk(b.x, b.y), pk(b.z, b.w) };
    return __builtin_bit_cast(f16x8, u);
}
static __device__ __forceinline__ float gi_e(uint2 g, int rr) {
    const uint wd = (rr < 2) ? g.x : g.y;
    return (rr & 1) ? f16hi(wd) : f16lo(wd);
}
#define PIN(v) asm volatile("" : "+v"(v))
#define MFMA(a, b, c) __builtin_amdgcn_mfma_f32_16x16x32_f16((a), (b), (c), 0, 0, 0)
// raw barrier: orders LDS only; global prefetch loads stay in flight
#define WAVEBAR() asm volatile("s_waitcnt lgkmcnt(0)\n\ts_barrier" ::: "memory")

// ---------- M = W_hh (384x128) @ nW2 (128x128), f32 ----------
__global__ __launch_bounds__(128) void mfuse(
    const float* __restrict__ W_hh, const float* __restrict__ nW2,
    float* __restrict__ M)
{
    __shared__ float wrow[NH];
    const int r = blockIdx.x;
    const int j = threadIdx.x;
    wrow[j] = W_hh[(size_t)r * NH + j];
    __syncthreads();
    float a0 = 0.0f, a1 = 0.0f, a2 = 0.0f, a3 = 0.0f;
#pragma unroll 8
    for (int k = 0; k < NH; k += 4) {
        a0 += wrow[k]     * nW2[(size_t)(k)     * NH + j];
        a1 += wrow[k + 1] * nW2[(size_t)(k + 1) * NH + j];
        a2 += wrow[k + 2] * nW2[(size_t)(k + 2) * NH + j];
        a3 += wrow[k + 3] * nW2[(size_t)(k + 3) * NH + j];
    }
    M[(size_t)r * NH + j] = (a0 + a1) + (a2 + a3);
}

// ---------- cv[r] = dot(W_hh[r], node_b2) ----------
__global__ __launch_bounds__(128) void cvk(
    const float* __restrict__ W_hh, const float* __restrict__ nb2,
    float* __restrict__ cv)
{
    const int r = blockIdx.x * 128 + threadIdx.x;   // 0..383
    const float* wr = W_hh + (size_t)r * NH;
    float a = 0.0f;
#pragma unroll 8
    for (int k = 0; k < NH; ++k) a += wr[k] * nb2[k];
    cv[r] = a;
}

// ---------- gi precompute: giu[t][b][row] (f16) = W_ih@x + folded biases ----------
// row g*128+j gets + (b_ih+b_hh)[g*128+j] for g<2 (r,z gates); + b_ih for g=2 (n gate).
__global__ __launch_bounds__(384) void gi_pre(
    const float* __restrict__ x,      // (B,T,D)
    const float* __restrict__ W_ih,   // (384,64)
    const float* __restrict__ b_ih,   // (384)
    const float* __restrict__ b_hh,   // (384)
    ushort* __restrict__ giu)         // (T,B,384)
{
    __shared__ uint xt[125][32];
    const int tid = threadIdx.x;
    const int b   = blockIdx.x;
    const int t0  = blockIdx.y * 125;

    uint wr[32];
    const float* wrow = W_ih + (size_t)tid * ND;
#pragma unroll
    for (int k = 0; k < 8; ++k) ld8(wrow + k * 8, wr + k * 4);
    const float badd = (tid < 256) ? (b_ih[tid] + b_hh[tid]) : b_ih[tid];

    for (int i = tid; i < 125 * 32; i += 384) {
        const int t = i >> 5, c = i & 31;
        const float2 v = *(const float2*)(x + ((size_t)b * NT + t0 + t) * ND + c * 2);
        xt[t][c] = pk(v.x, v.y);
    }
    __syncthreads();

    for (int t = 0; t < 125; ++t) {
        const uint4* xr = (const uint4*)&xt[t][0];
        float a0 = 0.0f, a1 = 0.0f;
#pragma unroll
        for (int k4 = 0; k4 < 8; ++k4) {
            const uint4 hv = xr[k4];
            a0 = fdot2u(wr[k4 * 4 + 0], hv.x, a0);
            a1 = fdot2u(wr[k4 * 4 + 1], hv.y, a1);
            a0 = fdot2u(wr[k4 * 4 + 2], hv.z, a0);
            a1 = fdot2u(wr[k4 * 4 + 3], hv.w, a1);
        }
        giu[((size_t)(t0 + t) * NB + b) * 384 + tid] =
            __builtin_bit_cast(ushort, (_Float16)(a0 + a1 + badd));
    }
}

// ---------- MFMA 2-phase scan, 2 rows/block interleaved between barriers ----------
__global__
__attribute__((amdgpu_flat_work_group_size(512, 512)))
__attribute__((amdgpu_waves_per_eu(2, 2)))
void gruode_scan_mfma(
    const float* __restrict__ tps,
    const int*   __restrict__ mask,
    const float* __restrict__ W_hh,
    const float* __restrict__ b_hh,
    const float* __restrict__ nW1,
    const float* __restrict__ nb1,
    const float* __restrict__ nW2,
    const float* __restrict__ nb2,
    const float* __restrict__ W_out,
    const float* __restrict__ b_out,
    const float* __restrict__ Mw,     // (384,128) = W_hh @ nW2
    const float* __restrict__ cv,     // (384)     = W_hh @ nb2
    const ushort* __restrict__ giu,   // (T,B,384) f16, biases folded
    float* __restrict__ out)          // (B,128)
{
    __shared__ __align__(16) _Float16 sh_h[2][2][NH];   // [pingpong][row][128]
    __shared__ __align__(16) _Float16 sh_tmp[2][NH];    // [row][128]
    __shared__ float sh_dt[NT];
    __shared__ uint  sh_mb[NT];

    const int tid  = threadIdx.x;
    const int w    = tid >> 6;        // wave 0..7 owns A-rows w*16..+15 of each set
    const int lane = tid & 63;
    const int n    = lane & 15;       // A row-within-tile / D col (cols replicated)
    const int kg   = lane >> 4;       // k-group; D rows kg*4+rr
    const int b0   = blockIdx.x * 2;
    const int jb   = w * 16 + kg * 4; // this lane's first output row j

    // ---- A-fragments (round-6/11-verified layout); live in AGPRs, MFMA reads in place
    f16x8 w1F[4], whrF[4], whzF[4], whnF[4];
    f16x8 w2F[4], mrF[4], mzF[4], mnF[4];
#pragma unroll
    for (int ks = 0; ks < 4; ++ks) {
        const int c   = ks * 32 + kg * 8;
        const int row = w * 16 + n;
        w1F[ks]  = ldWfrag(nW1  + (size_t)row         * NH + c);
        whrF[ks] = ldWfrag(W_hh + (size_t)row         * NH + c);
        whzF[ks] = ldWfrag(W_hh + (size_t)(row + 128) * NH + c);
        whnF[ks] = ldWfrag(W_hh + (size_t)(row + 256) * NH + c);
        w2F[ks]  = ldWfrag(nW2  + (size_t)row         * NH + c);
        mrF[ks]  = ldWfrag(Mw   + (size_t)row         * NH + c);
        mzF[ks]  = ldWfrag(Mw   + (size_t)(row + 128) * NH + c);
        mnF[ks]  = ldWfrag(Mw   + (size_t)(row + 256) * NH + c);
    }
#pragma unroll
    for (int ks = 0; ks < 4; ++ks) {
        PIN(w1F[ks]); PIN(whrF[ks]); PIN(whzF[ks]); PIN(whnF[ks]);
        PIN(w2F[ks]); PIN(mrF[ks]);  PIN(mzF[ks]);  PIN(mnF[ks]);
    }
    // ---- per-rr scalars (j = jb + rr); r/z/n-gate static biases folded into gi
    float bb1v[4], bb2v[4], bhnn[4], crv[4], czv[4], cnv[4];
#pragma unroll
    for (int rr = 0; rr < 4; ++rr) {
        const int j = jb + rr;
        bb1v[rr] = nb1[j];
        bb2v[rr] = nb2[j];
        bhnn[rr] = b_hh[j + 256];
        crv[rr]  = cv[j];
        czv[rr]  = cv[j + 128];
        cnv[rr]  = cv[j + 256];
    }

    // ---- stage dt + 2-row mask bits; zero h ping buffer
    for (int s = tid; s < NT; s += 512) {
        sh_dt[s] = (s == 0) ? 0.0f : (tps[s] - tps[s - 1]);
        sh_mb[s] = (uint)(mask[(size_t)b0 * NT + s] & 1) |
                   ((uint)(mask[(size_t)(b0 + 1) * NT + s] & 1) << 1);
    }
    if (tid < 128) ((uint*)sh_h)[tid] = 0u;   // sh_h[0][*][*] = 512 B
    __syncthreads();

    // ---- per-lane LDS byte offsets within one row's 256B vector
    const int rdk = kg * 16;                      // + {0,64,128,192}
    const int wOff = w * 32 + kg * 8;             // writer offset (uint2)
    const bool wr_lane = (n == 0);

    // ---- gi prefetch: 1 step deep (superstep >> latency)
    const size_t GSTR = (size_t)NB * 384;
    const ushort* gbA = giu + (size_t)b0 * 384 + jb;
    const ushort* gbB = gbA + 384;
    uint2 gAr = *(const uint2*)(gbA);
    uint2 gAz = *(const uint2*)(gbA + 128);
    uint2 gAn = *(const uint2*)(gbA + 256);
    uint2 gBr = *(const uint2*)(gbB);
    uint2 gBz = *(const uint2*)(gbB + 128);
    uint2 gBn = *(const uint2*)(gbB + 256);

    float hjA[4] = {0, 0, 0, 0}, hjB[4] = {0, 0, 0, 0};
    float hlA[4] = {0, 0, 0, 0}, hlB[4] = {0, 0, 0, 0};
    int   seenA = 0, seenB = 0;
    float dtc = sh_dt[0];
    uint  mwc = sh_mb[0];
    const f32x4 z4 = {0, 0, 0, 0};

    for (int s = 0; s < NT; ++s) {
        const int cur = s & 1, nxt = cur ^ 1;
        const uint mw = mwc;
        const int  mA = mw & 1, mB = (mw >> 1) & 1;
        const float dteA = seenA ? dtc : 0.0f;
        const float dteB = seenB ? dtc : 0.0f;

        // issue next-step gi prefetch (stays in flight across WAVEBARs)
        const int sn = (s + 1 < NT) ? (s + 1) : s;
        const ushort* gA2 = gbA + (size_t)sn * GSTR;
        const ushort* gB2 = gbB + (size_t)sn * GSTR;
        const uint2 pAr = *(const uint2*)(gA2);
        const uint2 pAz = *(const uint2*)(gA2 + 128);
        const uint2 pAn = *(const uint2*)(gA2 + 256);
        const uint2 pBr = *(const uint2*)(gB2);
        const uint2 pBz = *(const uint2*)(gB2 + 128);
        const uint2 pBn = *(const uint2*)(gB2 + 256);
        const float dt_n = sh_dt[sn];
        const uint  mw_n = sh_mb[sn];

        // ================= phase A (both rows) =================
        const char* hbA = (const char*)&sh_h[cur][0][0];
        const char* hbB = (const char*)&sh_h[cur][1][0];
        const f16x8 hA0 = *(const f16x8*)(hbA +       rdk);
        const f16x8 hA1 = *(const f16x8*)(hbA +  64 + rdk);
        const f16x8 hA2 = *(const f16x8*)(hbA + 128 + rdk);
        const f16x8 hA3 = *(const f16x8*)(hbA + 192 + rdk);
        const f16x8 hB0 = *(const f16x8*)(hbB +       rdk);
        const f16x8 hB1 = *(const f16x8*)(hbB +  64 + rdk);
        const f16x8 hB2 = *(const f16x8*)(hbB + 128 + rdk);
        const f16x8 hB3 = *(const f16x8*)(hbB + 192 + rdk);

        f32x4 D1A = MFMA(w1F[0], hA0, z4);
        D1A = MFMA(w1F[1], hA1, D1A);
        D1A = MFMA(w1F[2], hA2, D1A);
        D1A = MFMA(w1F[3], hA3, D1A);
        f32x4 D1B = MFMA(w1F[0], hB0, z4);
        D1B = MFMA(w1F[1], hB1, D1B);
        D1B = MFMA(w1F[2], hB2, D1B);
        D1B = MFMA(w1F[3], hB3, D1B);

        f32x4 DrA = z4, DzA = z4, DnA = z4;
        if (mA) {
            DrA = MFMA(whrF[0], hA0, z4); DrA = MFMA(whrF[1], hA1, DrA);
            DrA = MFMA(whrF[2], hA2, DrA); DrA = MFMA(whrF[3], hA3, DrA);
            DzA = MFMA(whzF[0], hA0, z4); DzA = MFMA(whzF[1], hA1, DzA);
            DzA = MFMA(whzF[2], hA2, DzA); DzA = MFMA(whzF[3], hA3, DzA);
            DnA = MFMA(whnF[0], hA0, z4); DnA = MFMA(whnF[1], hA1, DnA);
            DnA = MFMA(whnF[2], hA2, DnA); DnA = MFMA(whnF[3], hA3, DnA);
        }
        f32x4 DrB = z4, DzB = z4, DnB = z4;
        if (mB) {
            DrB = MFMA(whrF[0], hB0, z4); DrB = MFMA(whrF[1], hB1, DrB);
            DrB = MFMA(whrF[2], hB2, DrB); DrB = MFMA(whrF[3], hB3, DrB);
            DzB = MFMA(whzF[0], hB0, z4); DzB = MFMA(whzF[1], hB1, DzB);
            DzB = MFMA(whzF[2], hB2, DzB); DzB = MFMA(whzF[3], hB3, DzB);
            DnB = MFMA(whnF[0], hB0, z4); DnB = MFMA(whnF[1], hB1, DnB);
            DnB = MFMA(whnF[2], hB2, DnB); DnB = MFMA(whnF[3], hB3, DnB);
        }
        if (wr_lane) {
            *(uint2*)((char*)&sh_tmp[0][0] + wOff) = make_uint2(
                pk(tanh_f(D1A[0] + bb1v[0]), tanh_f(D1A[1] + bb1v[1])),
                pk(tanh_f(D1A[2] + bb1v[2]), tanh_f(D1A[3] + bb1v[3])));
            *(uint2*)((char*)&sh_tmp[1][0] + wOff) = make_uint2(
                pk(tanh_f(D1B[0] + bb1v[0]), tanh_f(D1B[1] + bb1v[1])),
                pk(tanh_f(D1B[2] + bb1v[2]), tanh_f(D1B[3] + bb1v[3])));
        }
        WAVEBAR();

        // ================= phase B (both rows) =================
        const char* tbA = (const char*)&sh_tmp[0][0];
        const char* tbB = (const char*)&sh_tmp[1][0];
        const f16x8 tA0 = *(const f16x8*)(tbA +       rdk);
        const f16x8 tA1 = *(const f16x8*)(tbA +  64 + rdk);
        const f16x8 tA2 = *(const f16x8*)(tbA + 128 + rdk);
        const f16x8 tA3 = *(const f16x8*)(tbA + 192 + rdk);
        const f16x8 tB0 = *(const f16x8*)(tbB +       rdk);
        const f16x8 tB1 = *(const f16x8*)(tbB +  64 + rdk);
        const f16x8 tB2 = *(const f16x8*)(tbB + 128 + rdk);
        const f16x8 tB3 = *(const f16x8*)(tbB + 192 + rdk);

        f32x4 D2A = MFMA(w2F[0], tA0, z4);
        D2A = MFMA(w2F[1], tA1, D2A);
        D2A = MFMA(w2F[2], tA2, D2A);
        D2A = MFMA(w2F[3], tA3, D2A);
        f32x4 D2B = MFMA(w2F[0], tB0, z4);
        D2B = MFMA(w2F[1], tB1, D2B);
        D2B = MFMA(w2F[2], tB2, D2B);
        D2B = MFMA(w2F[3], tB3, D2B);

        float hnA[4], hnB[4];
        if (mA) {
            f32x4 Mr = MFMA(mrF[0], tA0, z4);
            Mr = MFMA(mrF[1], tA1, Mr); Mr = MFMA(mrF[2], tA2, Mr); Mr = MFMA(mrF[3], tA3, Mr);
            f32x4 Mz = MFMA(mzF[0], tA0, z4);
            Mz = MFMA(mzF[1], tA1, Mz); Mz = MFMA(mzF[2], tA2, Mz); Mz = MFMA(mzF[3], tA3, Mz);
            f32x4 Mn = MFMA(mnF[0], tA0, z4);
            Mn = MFMA(mnF[1], tA1, Mn); Mn = MFMA(mnF[2], tA2, Mn); Mn = MFMA(mnF[3], tA3, Mn);
#pragma unroll
            for (int rr = 0; rr < 4; ++rr) {
                const float hode = hjA[rr] + dteA * (D2A[rr] + bb2v[rr]);
                const float sr = DrA[rr] + dteA * (Mr[rr] + crv[rr]) + gi_e(gAr, rr);
                const float sz = DzA[rr] + dteA * (Mz[rr] + czv[rr]) + gi_e(gAz, rr);
                const float hn = DnA[rr] + dteA * (Mn[rr] + cnv[rr]) + bhnn[rr];
                const float rg = sigmoid_f(sr);
                const float zg = sigmoid_f(sz);
                const float nn = tanh_f(gi_e(gAn, rr) + rg * hn);
                hnA[rr] = (1.0f - zg) * nn + zg * hode;
                hlA[rr] = hnA[rr];
            }
        } else {
#pragma unroll
            for (int rr = 0; rr < 4; ++rr)
                hnA[rr] = hjA[rr] + dteA * (D2A[rr] + bb2v[rr]);
        }
        if (mB) {
            f32x4 Mr = MFMA(mrF[0], tB0, z4);
            Mr = MFMA(mrF[1], tB1, Mr); Mr = MFMA(mrF[2], tB2, Mr); Mr = MFMA(mrF[3], tB3, Mr);
            f32x4 Mz = MFMA(mzF[0], tB0, z4);
            Mz = MFMA(mzF[1], tB1, Mz); Mz = MFMA(mzF[2], tB2, Mz); Mz = MFMA(mzF[3], tB3, Mz);
            f32x4 Mn = MFMA(mnF[0], tB0, z4);
            Mn = MFMA(mnF[1], tB1, Mn); Mn = MFMA(mnF[2], tB2, Mn); Mn = MFMA(mnF[3], tB3, Mn);
#pragma unroll
            for (int rr = 0; rr < 4; ++rr) {
                const float hode = hjB[rr] + dteB * (D2B[rr] + bb2v[rr]);
                const float sr = DrB[rr] + dteB * (Mr[rr] + crv[rr]) + gi_e(gBr, rr);
                const float sz = DzB[rr] + dteB * (Mz[rr] + czv[rr]) + gi_e(gBz, rr);
                const float hn = DnB[rr] + dteB * (Mn[rr] + cnv[rr]) + bhnn[rr];
                const float rg = sigmoid_f(sr);
                const float zg = sigmoid_f(sz);
                const float nn = tanh_f(gi_e(gBn, rr) + rg * hn);
                hnB[rr] = (1.0f - zg) * nn + zg * hode;
                hlB[rr] = hnB[rr];
            }
        } else {
#pragma unroll
            for (int rr = 0; rr < 4; ++rr)
                hnB[rr] = hjB[rr] + dteB * (D2B[rr] + bb2v[rr]);
        }
#pragma unroll
        for (int rr = 0; rr < 4; ++rr) { hjA[rr] = hnA[rr]; hjB[rr] = hnB[rr]; }
        if (wr_lane) {
            *(uint2*)((char*)&sh_h[nxt][0][0] + wOff) =
                make_uint2(pk(hnA[0], hnA[1]), pk(hnA[2], hnA[3]));
            *(uint2*)((char*)&sh_h[nxt][1][0] + wOff) =
                make_uint2(pk(hnB[0], hnB[1]), pk(hnB[2], hnB[3]));
        }
        seenA |= mA; seenB |= mB;
        gAr = pAr; gAz = pAz; gAn = pAn;
        gBr = pBr; gBz = pBz; gBn = pBn;
        dtc = dt_n; mwc = mw_n;
        WAVEBAR();
    }

    // ---- epilogue: out = W_out @ h_last + b_out, per row
    if (wr_lane) {
        *(uint2*)((char*)&sh_tmp[0][0] + wOff) =
            make_uint2(pk(hlA[0], hlA[1]), pk(hlA[2], hlA[3]));
        *(uint2*)((char*)&sh_tmp[1][0] + wOff) =
            make_uint2(pk(hlB[0], hlB[1]), pk(hlB[2], hlB[3]));
    }
    __syncthreads();
    const f16x8 wo0 = ldWfrag(W_out + (size_t)(w * 16 + n) * NH +  0 + kg * 8);
    const f16x8 wo1 = ldWfrag(W_out + (size_t)(w * 16 + n) * NH + 32 + kg * 8);
    const f16x8 wo2 = ldWfrag(W_out + (size_t)(w * 16 + n) * NH + 64 + kg * 8);
    const f16x8 wo3 = ldWfrag(W_out + (size_t)(w * 16 + n) * NH + 96 + kg * 8);
#pragma unroll
    for (int row = 0; row < 2; ++row) {
        const char* eb = (const char*)&sh_tmp[row][0];
        f32x4 Do = MFMA(wo0, *(const f16x8*)(eb +       rdk), z4);
        Do = MFMA(wo1, *(const f16x8*)(eb +  64 + rdk), Do);
        Do = MFMA(wo2, *(const f16x8*)(eb + 128 + rdk), Do);
        Do = MFMA(wo3, *(const f16x8*)(eb + 192 + rdk), Do);
        if (wr_lane) {
            float4 o;
            o.x = Do[0] + b_out[jb];
            o.y = Do[1] + b_out[jb + 1];
            o.z = Do[2] + b_out[jb + 2];
            o.w = Do[3] + b_out[jb + 3];
            *(float4*)(out + (size_t)(b0 + row) * NH + jb) = o;
        }
    }
}

// ---------- fallback VALU scan (round-10 structure, self-contained) ----------
__global__
__attribute__((amdgpu_flat_work_group_size(512, 512)))
__attribute__((amdgpu_waves_per_eu(2, 2)))
void gruode_scan_valu(
    const float* __restrict__ x,
    const float* __restrict__ tps,
    const int*   __restrict__ mask,
    const float* __restrict__ W_ih,
    const float* __restrict__ W_hh,
    const float* __restrict__ b_ih,
    const float* __restrict__ b_hh,
    const float* __restrict__ nW1,
    const float* __restrict__ nb1,
    const float* __restrict__ nW2,
    const float* __restrict__ nb2,
    const float* __restrict__ W_out,
    const float* __restrict__ b_out,
    const float* __restrict__ Mw,
    float* __restrict__ out)
{
    __shared__ __align__(16) _Float16 sh_h[2][NH];
    __shared__ __align__(16) _Float16 sh_tmp[NH];
    __shared__ float sh_eo[NH];
    __shared__ float sh_dt[NT];
    __shared__ int   sh_m[NT];

    const int tid = threadIdx.x;
    const int j   = tid >> 2;
    const int q   = tid & 3;
    const int b   = blockIdx.x;
    const int kb  = q * 32;
    const int qb  = q * 64;

#define WSEL(i) (((i) + (q >> 1)) & 3)

    uint w1[4][4], w2[4][4], whr[4][4], whz[4][4], whn[4][4];
    uint mr[4][4], mz[4][4], mn[4][4];
#pragma unroll
    for (int i = 0; i < 4; ++i) {
        const int c = kb + (WSEL(i) << 3);
        ld8(nW1  + (size_t)(j      ) * NH + c, w1[i]);
        ld8(nW2  + (size_t)(j      ) * NH + c, w2[i]);
        ld8(W_hh + (size_t)(j      ) * NH + c, whr[i]);
        ld8(W_hh + (size_t)(j + 128) * NH + c, whz[i]);
        ld8(W_hh + (size_t)(j + 256) * NH + c, whn[i]);
        ld8(Mw   + (size_t)(j      ) * NH + c, mr[i]);
        ld8(Mw   + (size_t)(j + 128) * NH + c, mz[i]);
        ld8(Mw   + (size_t)(j + 256) * NH + c, mn[i]);
    }
    uint wir[8], wiz[8], win[8];
    {
        const int kbi = q * 16;
        ld8(W_ih + (size_t)(j      ) * ND + kbi,     wir);
        ld8(W_ih + (size_t)(j      ) * ND + kbi + 8, wir + 4);
        ld8(W_ih + (size_t)(j + 128) * ND + kbi,     wiz);
        ld8(W_ih + (size_t)(j + 128) * ND + kbi + 8, wiz + 4);
        ld8(W_ih + (size_t)(j + 256) * ND + kbi,     win);
        ld8(W_ih + (size_t)(j + 256) * ND + kbi + 8, win + 4);
    }
    float bb1   = nb1[j];
    float bb2   = nb2[j];
    float brz_r = b_ih[j]       + b_hh[j];
    float brz_z = b_ih[j + 128] + b_hh[j + 128];
    float bin_n = b_ih[j + 256];
    float bhn_n = b_hh[j + 256];

    float cr = 0.0f, cz = 0.0f, cn = 0.0f;
    {
        uint b2p[4];
#pragma unroll
        for (int i = 0; i < 4; ++i) {
            const int c = kb + (WSEL(i) << 3);
            ld8(nb2 + c, b2p);
#pragma unroll
            for (int k = 0; k < 4; ++k) {
                cr = fdot2u(whr[i][k], b2p[k], cr);
                cz = fdot2u(whz[i][k], b2p[k], cz);
                cn = fdot2u(whn[i][k], b2p[k], cn);
            }
        }
        cr = qsum(cr); cz = qsum(cz); cn = qsum(cn);
    }

    for (int s = tid; s < NT; s += 512) {
        sh_dt[s] = (s == 0) ? 0.0f : (tps[s] - tps[s - 1]);
        sh_m[s]  = mask[b * NT + s];
    }
    if (tid < NH) sh_h[0][tid] = (_Float16)0.0f;
    __syncthreads();

    float hj = 0.0f, hlast = 0.0f;
    int   seen = 0;

    const float* xbase = x + (size_t)b * NT * ND + q * 16;
    float4 xc0 = *(const float4*)(xbase);
    float4 xc1 = *(const float4*)(xbase + 4);
    float4 xc2 = *(const float4*)(xbase + 8);
    float4 xc3 = *(const float4*)(xbase + 12);
    float dtc = sh_dt[0];
    int   mc  = sh_m[0];

    for (int s = 0; s < NT; ++s) {
        const int cur = s & 1, nxt = cur ^ 1;
        const int sn_ = (s + 1 < NT) ? (s + 1) : s;
        const float* xr = xbase + (size_t)sn_ * ND;
        const float4 xn0 = *(const float4*)(xr);
        const float4 xn1 = *(const float4*)(xr + 4);
        const float4 xn2 = *(const float4*)(xr + 8);
        const float4 xn3 = *(const float4*)(xr + 12);
        const float dt_n = sh_dt[sn_];
        const int   m_n  = sh_m[sn_];

        const int   m   = mc;
        const float dte = seen ? dtc : 0.0f;

        uint xh[8];
        xh[0] = pk(xc0.x, xc0.y); xh[1] = pk(xc0.z, xc0.w);
        xh[2] = pk(xc1.x, xc1.y); xh[3] = pk(xc1.z, xc1.w);
        xh[4] = pk(xc2.x, xc2.y); xh[5] = pk(xc2.z, xc2.w);
        xh[6] = pk(xc3.x, xc3.y); xh[7] = pk(xc3.z, xc3.w);
        float grf = 0.0f, gzf = 0.0f, gnf = 0.0f;
#pragma unroll
        for (int k = 0; k < 8; ++k) {
            grf = fdot2u(wir[k], xh[k], grf);
            gzf = fdot2u(wiz[k], xh[k], gzf);
            gnf = fdot2u(win[k], xh[k], gnf);
        }

        float a1 = 0.0f, ahr = 0.0f, ahz = 0.0f, ahn = 0.0f;
        const char* hb = (const char*)&sh_h[cur][0];
#pragma unroll
        for (int i = 0; i < 4; ++i) {
            const uint4 hv = *(const uint4*)(hb + qb + WSEL(i) * 16);
            a1  = fdot2u(w1[i][0],  hv.x, a1);  a1  = fdot2u(w1[i][1],  hv.y, a1);
            a1  = fdot2u(w1[i][2],  hv.z, a1);  a1  = fdot2u(w1[i][3],  hv.w, a1);
            ahr = fdot2u(whr[i][0], hv.x, ahr); ahr = fdot2u(whr[i][1], hv.y, ahr);
            ahr = fdot2u(whr[i][2], hv.z, ahr); ahr = fdot2u(whr[i][3], hv.w, ahr);
            ahz = fdot2u(whz[i][0], hv.x, ahz); ahz = fdot2u(whz[i][1], hv.y, ahz);
            ahz = fdot2u(whz[i][2], hv.z, ahz); ahz = fdot2u(whz[i][3], hv.w, ahz);
            ahn = fdot2u(whn[i][0], hv.x, ahn); ahn = fdot2u(whn[i][1], hv.y, ahn);
            ahn = fdot2u(whn[i][2], hv.z, ahn); ahn = fdot2u(whn[i][3], hv.w, ahn);
        }
        const float a1q = qsum(a1);
        if (q == 0) sh_tmp[j] = (_Float16)tanh_f(a1q + bb1);
        WAVEBAR();

        float a2 = 0.0f, amr = 0.0f, amz = 0.0f, amn = 0.0f;
#pragma unroll
        for (int i = 0; i < 4; ++i) {
            const uint4 tv = *(const uint4*)((const char*)sh_tmp + qb + WSEL(i) * 16);
            a2  = fdot2u(w2[i][0], tv.x, a2);  a2  = fdot2u(w2[i][1], tv.y, a2);
            a2  = fdot2u(w2[i][2], tv.z, a2);  a2  = fdot2u(w2[i][3], tv.w, a2);
            amr = fdot2u(mr[i][0], tv.x, amr); amr = fdot2u(mr[i][1], tv.y, amr);
            amr = fdot2u(mr[i][2], tv.z, amr); amr = fdot2u(mr[i][3], tv.w, amr);
            amz = fdot2u(mz[i][0], tv.x, amz); amz = fdot2u(mz[i][1], tv.y, amz);
            amz = fdot2u(mz[i][2], tv.z, amz); amz = fdot2u(mz[i][3], tv.w, amz);
            amn = fdot2u(mn[i][0], tv.x, amn); amn = fdot2u(mn[i][1], tv.y, amn);
            amn = fdot2u(mn[i][2], tv.z, amn); amn = fdot2u(mn[i][3], tv.w, amn);
        }
        const float a2q  = qsum(a2);
        const float hode = hj + dte * (a2q + bb2);
        const float sr_t = qsum(ahr + dte * amr) + dte * cr;
        const float sz_t = qsum(ahz + dte * amz) + dte * cz;
        const float hn_t = qsum(ahn + dte * amn) + dte * cn;

        const float r = sigmoid_f(sr_t + grf + brz_r);
        const float z = sigmoid_f(sz_t + gzf + brz_z);
        const float n = tanh_f(gnf + bin_n + r * (hn_t + bhn_n));
        const float hnew = m ? ((1.0f - z) * n + z * hode) : hode;

        if (q == 0) sh_h[nxt][j] = (_Float16)hnew;
        hj = hnew;
        if (m) hlast = hnew;
        seen |= m;
        xc0 = xn0; xc1 = xn1; xc2 = xn2; xc3 = xn3;
        dtc = dt_n; mc = m_n;
        WAVEBAR();
    }

    if (q == 0) sh_eo[j] = hlast;
    __syncthreads();
    float ao = 0.0f;
#pragma unroll
    for (int i = 0; i < 8; ++i) {
        const int c = kb + (((i + 2 * q) & 7) << 2);
        const float4 wv = *(const float4*)(W_out + (size_t)j * NH + c);
        const float4 hv = *(const float4*)(sh_eo + c);
        ao += wv.x * hv.x + wv.y * hv.y + wv.z * hv.z + wv.w * hv.w;
    }
    ao = qsum(ao);
    if (q == 0) out[(size_t)b * NH + j] = ao + b_out[j];
}

extern "C" void kernel_launch(void* const* d_in, const int* in_sizes, int n_in,
                              void* d_out, int out_size, void* d_ws, size_t ws_size,
                              hipStream_t stream) {
    const float* x     = (const float*)d_in[0];
    const float* tps   = (const float*)d_in[1];
    const int*   mask  = (const int*)  d_in[2];
    const float* W_ih  = (const float*)d_in[3];
    const float* W_hh  = (const float*)d_in[4];
    const float* b_ih  = (const float*)d_in[5];
    const float* b_hh  = (const float*)d_in[6];
    const float* nW1   = (const float*)d_in[7];
    const float* nb1   = (const float*)d_in[8];
    const float* nW2   = (const float*)d_in[9];
    const float* nb2   = (const float*)d_in[10];
    const float* W_out = (const float*)d_in[11];
    const float* b_out = (const float*)d_in[12];
    float* out = (float*)d_out;

    const size_t M_BYTES  = (size_t)384 * NH * sizeof(float);        // 196,608
    const size_t CV_OFF   = M_BYTES;                                  // cv: 1,536 B
    const size_t GI_OFF   = M_BYTES + 4096;
    const size_t GI_BYTES = (size_t)NT * NB * 384 * sizeof(ushort);  // 196,608,000
    float*  Mw  = (float*)d_ws;
    float*  cvp = (float*)((char*)d_ws + CV_OFF);
    ushort* giu = (ushort*)((char*)d_ws + GI_OFF);

    mfuse<<<dim3(384), dim3(128), 0, stream>>>(W_hh, nW2, Mw);
    if (ws_size >= GI_OFF + GI_BYTES) {
        cvk<<<dim3(3), dim3(128), 0, stream>>>(W_hh, nb2, cvp);
        gi_pre<<<dim3(NB, 8), dim3(384), 0, stream>>>(x, W_ih, b_ih, b_hh, giu);
        gruode_scan_mfma<<<dim3(NBLK), dim3(512), 0, stream>>>(
            tps, mask, W_hh, b_hh, nW1, nb1, nW2, nb2,
            W_out, b_out, Mw, cvp, giu, out);
    } else {
        gruode_scan_valu<<<dim3(NB), dim3(512), 0, stream>>>(
            x, tps, mask, W_ih, W_hh, b_ih, b_hh,
            nW1, nb1, nW2, nb2, W_out, b_out, Mw, out);
    }
}

// Round 15
// 1032.164 us; speedup vs baseline: 2.6214x; 2.6214x over previous
//
#include <hip/hip_runtime.h>

#define NB 256
#define NT 1000
#define ND 64
#define NH 128

typedef _Float16 h2 __attribute__((ext_vector_type(2)));

static __device__ __forceinline__ uint pk(float a, float b) {
    return __builtin_bit_cast(uint, __builtin_amdgcn_cvt_pkrtz(a, b));
}
static __device__ __forceinline__ float fdot2u(uint a, uint b, float c) {
#if __has_builtin(__builtin_amdgcn_fdot2)
    return __builtin_amdgcn_fdot2(__builtin_bit_cast(h2, a),
                                  __builtin_bit_cast(h2, b), c, false);
#else
    h2 ha = __builtin_bit_cast(h2, a), hb = __builtin_bit_cast(h2, b);
    return c + (float)ha.x * (float)hb.x + (float)ha.y * (float)hb.y;
#endif
}
static __device__ __forceinline__ float f16lo(uint u) {
    return (float)__builtin_bit_cast(h2, u).x;
}
static __device__ __forceinline__ float f16hi(uint u) {
    return (float)__builtin_bit_cast(h2, u).y;
}
static __device__ __forceinline__ float sigmoid_f(float x) {
    float e = __builtin_amdgcn_exp2f(-1.4426950408889634f * x);
    return __builtin_amdgcn_rcpf(1.0f + e);
}
static __device__ __forceinline__ float tanh_f(float x) {
    float e = __builtin_amdgcn_exp2f(-2.8853900817779268f * x);
    return 2.0f * __builtin_amdgcn_rcpf(1.0f + e) - 1.0f;
}
// quad butterfly sum via DPP
static __device__ __forceinline__ float qsum(float v) {
    int a = __builtin_amdgcn_update_dpp(0, __builtin_bit_cast(int, v),
                                        0xB1, 0xF, 0xF, true); // quad_perm(1,0,3,2)
    v += __builtin_bit_cast(float, a);
    int b = __builtin_amdgcn_update_dpp(0, __builtin_bit_cast(int, v),
                                        0x4E, 0xF, 0xF, true); // quad_perm(2,3,0,1)
    v += __builtin_bit_cast(float, b);
    return v;
}
// load 8 consecutive f32, pack to 4 f16x2 regs
static __device__ __forceinline__ void ld8(const float* p, uint* d) {
    const float4 A = *(const float4*)p;
    const float4 B = *(const float4*)(p + 4);
    d[0] = pk(A.x, A.y); d[1] = pk(A.z, A.w);
    d[2] = pk(B.x, B.y); d[3] = pk(B.z, B.w);
}
#define PIN(v) asm volatile("" : "+v"(v))
// raw barrier: orders LDS only; global prefetch loads stay in flight
#define WAVEBAR() asm volatile("s_waitcnt lgkmcnt(0)\n\ts_barrier" ::: "memory")

// ---------- M = W_hh (384x128) @ nW2 (128x128), f32 ----------
__global__ __launch_bounds__(128) void mfuse(
    const float* __restrict__ W_hh, const float* __restrict__ nW2,
    float* __restrict__ M)
{
    __shared__ float wrow[NH];
    const int r = blockIdx.x;      // 0..383
    const int j = threadIdx.x;     // 0..127
    wrow[j] = W_hh[(size_t)r * NH + j];
    __syncthreads();
    float a0 = 0.0f, a1 = 0.0f, a2 = 0.0f, a3 = 0.0f;
#pragma unroll 8
    for (int k = 0; k < NH; k += 4) {
        a0 += wrow[k]     * nW2[(size_t)(k)     * NH + j];
        a1 += wrow[k + 1] * nW2[(size_t)(k + 1) * NH + j];
        a2 += wrow[k + 2] * nW2[(size_t)(k + 2) * NH + j];
        a3 += wrow[k + 3] * nW2[(size_t)(k + 3) * NH + j];
    }
    M[(size_t)r * NH + j] = (a0 + a1) + (a2 + a3);
}

// ---------- gi precompute: giu[t][b][row] (f16) = W_ih@x + folded biases ----------
// row g*128+j gets +(b_ih+b_hh)[row] for g<2 (r,z gates); +b_ih[row] for g=2 (n gate).
// (verified in round 14: absmax unchanged)
__global__ __launch_bounds__(384) void gi_pre(
    const float* __restrict__ x,      // (B,T,D)
    const float* __restrict__ W_ih,   // (384,64)
    const float* __restrict__ b_ih,   // (384)
    const float* __restrict__ b_hh,   // (384)
    ushort* __restrict__ giu)         // (T,B,384)
{
    __shared__ uint xt[125][32];      // f16-packed x tile (16 KB)
    const int tid = threadIdx.x;      // W_ih row
    const int b   = blockIdx.x;
    const int t0  = blockIdx.y * 125;

    uint wr[32];
    const float* wrow = W_ih + (size_t)tid * ND;
#pragma unroll
    for (int k = 0; k < 8; ++k) ld8(wrow + k * 8, wr + k * 4);
    const float badd = (tid < 256) ? (b_ih[tid] + b_hh[tid]) : b_ih[tid];

    for (int i = tid; i < 125 * 32; i += 384) {
        const int t = i >> 5, c = i & 31;
        const float2 v = *(const float2*)(x + ((size_t)b * NT + t0 + t) * ND + c * 2);
        xt[t][c] = pk(v.x, v.y);
    }
    __syncthreads();

    for (int t = 0; t < 125; ++t) {
        const uint4* xr = (const uint4*)&xt[t][0];   // broadcast reads
        float a0 = 0.0f, a1 = 0.0f;
#pragma unroll
        for (int k4 = 0; k4 < 8; ++k4) {
            const uint4 hv = xr[k4];
            a0 = fdot2u(wr[k4 * 4 + 0], hv.x, a0);
            a1 = fdot2u(wr[k4 * 4 + 1], hv.y, a1);
            a0 = fdot2u(wr[k4 * 4 + 2], hv.z, a0);
            a1 = fdot2u(wr[k4 * 4 + 3], hv.w, a1);
        }
        giu[((size_t)(t0 + t) * NB + b) * 384 + tid] =
            __builtin_bit_cast(ushort, (_Float16)(a0 + a1 + badd));
    }
}

// ---------- fused 2-phase scan (round-10 structure + m==0 fast path) ----------
template<int GI>
__global__
__attribute__((amdgpu_flat_work_group_size(512, 512)))
__attribute__((amdgpu_waves_per_eu(2, 2)))
void gruode_scan(
    const float* __restrict__ x,      // (B,T,D)  (GI=0 only)
    const float* __restrict__ tps,    // (T)
    const int*   __restrict__ mask,   // (B,T)
    const float* __restrict__ W_ih,   // (384,64)  (GI=0 only)
    const float* __restrict__ W_hh,   // (384,128)
    const float* __restrict__ b_ih,   // (384)
    const float* __restrict__ b_hh,   // (384)
    const float* __restrict__ nW1,    // (128,128)
    const float* __restrict__ nb1,    // (128)
    const float* __restrict__ nW2,    // (128,128)
    const float* __restrict__ nb2,    // (128)
    const float* __restrict__ W_out,  // (128,128)
    const float* __restrict__ b_out,  // (128)
    const float* __restrict__ Mw,     // (384,128) = W_hh @ nW2
    const ushort* __restrict__ giu,   // (T,B,384) f16, biases folded (GI=1)
    float* __restrict__ out)          // (B,128)
{
    __shared__ __align__(16) _Float16 sh_h[2][NH];
    __shared__ __align__(16) _Float16 sh_tmp[NH];
    __shared__ float sh_eo[NH];
    __shared__ float sh_dt[NT];
    __shared__ int   sh_m[NT];

    const int tid = threadIdx.x;
    const int j   = tid >> 2;   // output row 0..127
    const int q   = tid & 3;    // K-quarter
    const int b   = blockIdx.x;
    const int kb  = q * 32;     // f16 col base
    const int qb  = q * 64;     // byte base within 128-f16 row

#define WSEL(i) (((i) + (q >> 1)) & 3)   // verified conflict-free rotation

    // ---- stage weights (8 fragment sets = 128 u32) ----
    uint w1[4][4], w2[4][4], whr[4][4], whz[4][4], whn[4][4];
    uint mr[4][4], mz[4][4], mn[4][4];
#pragma unroll
    for (int i = 0; i < 4; ++i) {
        const int c = kb + (WSEL(i) << 3);
        ld8(nW1  + (size_t)(j      ) * NH + c, w1[i]);
        ld8(nW2  + (size_t)(j      ) * NH + c, w2[i]);
        ld8(W_hh + (size_t)(j      ) * NH + c, whr[i]);
        ld8(W_hh + (size_t)(j + 128) * NH + c, whz[i]);
        ld8(W_hh + (size_t)(j + 256) * NH + c, whn[i]);
        ld8(Mw   + (size_t)(j      ) * NH + c, mr[i]);
        ld8(Mw   + (size_t)(j + 128) * NH + c, mz[i]);
        ld8(Mw   + (size_t)(j + 256) * NH + c, mn[i]);
    }
    uint wir[8], wiz[8], win[8];
    if constexpr (!GI) {
        const int kbi = q * 16;
        ld8(W_ih + (size_t)(j      ) * ND + kbi,     wir);
        ld8(W_ih + (size_t)(j      ) * ND + kbi + 8, wir + 4);
        ld8(W_ih + (size_t)(j + 128) * ND + kbi,     wiz);
        ld8(W_ih + (size_t)(j + 128) * ND + kbi + 8, wiz + 4);
        ld8(W_ih + (size_t)(j + 256) * ND + kbi,     win);
        ld8(W_ih + (size_t)(j + 256) * ND + kbi + 8, win + 4);
    }
    float bb1   = nb1[j];
    float bb2   = nb2[j];
    float brz_r = b_ih[j]       + b_hh[j];        // GI=0 path only
    float brz_z = b_ih[j + 128] + b_hh[j + 128];  // GI=0 path only
    float bin_n = b_ih[j + 256];                  // GI=0 path only
    float bhn_n = b_hh[j + 256];

    // ---- cvec = W_hh @ node_b2 (per own j), from resident fragments ----
    float cr = 0.0f, cz = 0.0f, cn = 0.0f;
    {
        uint b2p[4];
#pragma unroll
        for (int i = 0; i < 4; ++i) {
            const int c = kb + (WSEL(i) << 3);
            ld8(nb2 + c, b2p);
#pragma unroll
            for (int k = 0; k < 4; ++k) {
                cr = fdot2u(whr[i][k], b2p[k], cr);
                cz = fdot2u(whz[i][k], b2p[k], cz);
                cn = fdot2u(whn[i][k], b2p[k], cn);
            }
        }
        cr = qsum(cr); cz = qsum(cz); cn = qsum(cn);
    }

#pragma unroll
    for (int i = 0; i < 4; ++i)
#pragma unroll
        for (int k = 0; k < 4; ++k) {
            PIN(w1[i][k]); PIN(w2[i][k]);
            PIN(whr[i][k]); PIN(whz[i][k]); PIN(whn[i][k]);
            PIN(mr[i][k]); PIN(mz[i][k]); PIN(mn[i][k]);
        }
    PIN(bb1); PIN(bb2); PIN(bhn_n);
    PIN(cr); PIN(cz); PIN(cn);

    // ---- stage dt / mask; init h ----
    for (int s = tid; s < NT; s += 512) {
        sh_dt[s] = (s == 0) ? 0.0f : (tps[s] - tps[s - 1]);
        sh_m[s]  = mask[b * NT + s];
    }
    if (tid < NH) sh_h[0][tid] = (_Float16)0.0f;
    __syncthreads();

    float hj = 0.0f, hlast = 0.0f;
    int   seen = 0;

    // gi prefetch, 2 steps deep
    const size_t GSTR = (size_t)NB * 384;
    const ushort* gb = giu + (size_t)b * 384 + j;
    ushort c_r, c_z, c_n, n_r, n_z, n_n;
    const float* xbase = x + (size_t)b * NT * ND + q * 16;
    float4 xc0, xc1, xc2, xc3;
    if constexpr (GI) {
        c_r = gb[0];           c_z = gb[128];           c_n = gb[256];
        n_r = gb[GSTR];        n_z = gb[GSTR + 128];    n_n = gb[GSTR + 256];
    } else {
        xc0 = *(const float4*)(xbase);
        xc1 = *(const float4*)(xbase + 4);
        xc2 = *(const float4*)(xbase + 8);
        xc3 = *(const float4*)(xbase + 12);
    }
    float dtc = sh_dt[0];
    int   mc  = sh_m[0];

    for (int s = 0; s < NT; ++s) {
        const int cur = s & 1, nxt = cur ^ 1;

        // issue prefetches (stay in flight across raw barriers)
        ushort p_r, p_z, p_n;
        float4 xn0, xn1, xn2, xn3;
        if constexpr (GI) {
            const int sp = (s + 2 < NT) ? (s + 2) : (NT - 1);
            const ushort* g2 = gb + (size_t)sp * GSTR;
            p_r = g2[0]; p_z = g2[128]; p_n = g2[256];
        } else {
            const int sn_ = (s + 1 < NT) ? (s + 1) : s;
            const float* xr = xbase + (size_t)sn_ * ND;
            xn0 = *(const float4*)(xr);
            xn1 = *(const float4*)(xr + 4);
            xn2 = *(const float4*)(xr + 8);
            xn3 = *(const float4*)(xr + 12);
        }
        const int sn = (s + 1 < NT) ? (s + 1) : s;
        const float dt_n = sh_dt[sn];
        const int   m_n  = sh_m[sn];

        const int   m   = mc;                  // uniform per block
        const float dte = seen ? dtc : 0.0f;   // r_fill freeze

        // input-gate contributions (biases folded in giu for GI=1)
        float grf, gzf, gnf;
        if constexpr (GI) {
            grf = (float)__builtin_bit_cast(_Float16, c_r);
            gzf = (float)__builtin_bit_cast(_Float16, c_z);
            gnf = (float)__builtin_bit_cast(_Float16, c_n);
        } else {
            uint xh[8];
            xh[0] = pk(xc0.x, xc0.y); xh[1] = pk(xc0.z, xc0.w);
            xh[2] = pk(xc1.x, xc1.y); xh[3] = pk(xc1.z, xc1.w);
            xh[4] = pk(xc2.x, xc2.y); xh[5] = pk(xc2.z, xc2.w);
            xh[6] = pk(xc3.x, xc3.y); xh[7] = pk(xc3.z, xc3.w);
            grf = gzf = gnf = 0.0f;
            if (m) {
#pragma unroll
                for (int k = 0; k < 8; ++k) {
                    grf = fdot2u(wir[k], xh[k], grf);
                    gzf = fdot2u(wiz[k], xh[k], gzf);
                    gnf = fdot2u(win[k], xh[k], gnf);
                }
            }
        }

        // ---- phase A: a1 = W1 h ; if(m) AH = W_hh h (same LDS reads) ----
        float a1 = 0.0f, ahr = 0.0f, ahz = 0.0f, ahn = 0.0f;
        const char* hb = (const char*)&sh_h[cur][0];
        if (m) {
#pragma unroll
            for (int i = 0; i < 4; ++i) {
                const uint4 hv = *(const uint4*)(hb + qb + WSEL(i) * 16);
                a1  = fdot2u(w1[i][0],  hv.x, a1);  a1  = fdot2u(w1[i][1],  hv.y, a1);
                a1  = fdot2u(w1[i][2],  hv.z, a1);  a1  = fdot2u(w1[i][3],  hv.w, a1);
                ahr = fdot2u(whr[i][0], hv.x, ahr); ahr = fdot2u(whr[i][1], hv.y, ahr);
                ahr = fdot2u(whr[i][2], hv.z, ahr); ahr = fdot2u(whr[i][3], hv.w, ahr);
                ahz = fdot2u(whz[i][0], hv.x, ahz); ahz = fdot2u(whz[i][1], hv.y, ahz);
                ahz = fdot2u(whz[i][2], hv.z, ahz); ahz = fdot2u(whz[i][3], hv.w, ahz);
                ahn = fdot2u(whn[i][0], hv.x, ahn); ahn = fdot2u(whn[i][1], hv.y, ahn);
                ahn = fdot2u(whn[i][2], hv.z, ahn); ahn = fdot2u(whn[i][3], hv.w, ahn);
            }
        } else {
#pragma unroll
            for (int i = 0; i < 4; ++i) {
                const uint4 hv = *(const uint4*)(hb + qb + WSEL(i) * 16);
                a1 = fdot2u(w1[i][0], hv.x, a1); a1 = fdot2u(w1[i][1], hv.y, a1);
                a1 = fdot2u(w1[i][2], hv.z, a1); a1 = fdot2u(w1[i][3], hv.w, a1);
            }
        }
        const float a1q = qsum(a1);
        if (q == 0) sh_tmp[j] = (_Float16)tanh_f(a1q + bb1);
        WAVEBAR();

        // ---- phase B: a2 = W2 tmp ; if(m) AM = M tmp ; gates ----
        float a2 = 0.0f, amr = 0.0f, amz = 0.0f, amn = 0.0f;
        if (m) {
#pragma unroll
            for (int i = 0; i < 4; ++i) {
                const uint4 tv = *(const uint4*)((const char*)sh_tmp + qb + WSEL(i) * 16);
                a2  = fdot2u(w2[i][0], tv.x, a2);  a2  = fdot2u(w2[i][1], tv.y, a2);
                a2  = fdot2u(w2[i][2], tv.z, a2);  a2  = fdot2u(w2[i][3], tv.w, a2);
                amr = fdot2u(mr[i][0], tv.x, amr); amr = fdot2u(mr[i][1], tv.y, amr);
                amr = fdot2u(mr[i][2], tv.z, amr); amr = fdot2u(mr[i][3], tv.w, amr);
                amz = fdot2u(mz[i][0], tv.x, amz); amz = fdot2u(mz[i][1], tv.y, amz);
                amz = fdot2u(mz[i][2], tv.z, amz); amz = fdot2u(mz[i][3], tv.w, amz);
                amn = fdot2u(mn[i][0], tv.x, amn); amn = fdot2u(mn[i][1], tv.y, amn);
                amn = fdot2u(mn[i][2], tv.z, amn); amn = fdot2u(mn[i][3], tv.w, amn);
            }
        } else {
#pragma unroll
            for (int i = 0; i < 4; ++i) {
                const uint4 tv = *(const uint4*)((const char*)sh_tmp + qb + WSEL(i) * 16);
                a2 = fdot2u(w2[i][0], tv.x, a2); a2 = fdot2u(w2[i][1], tv.y, a2);
                a2 = fdot2u(w2[i][2], tv.z, a2); a2 = fdot2u(w2[i][3], tv.w, a2);
            }
        }
        const float a2q  = qsum(a2);
        const float hode = hj + dte * (a2q + bb2);

        float hnew;
        if (m) {
            const float sr_t = qsum(ahr + dte * amr) + dte * cr;
            const float sz_t = qsum(ahz + dte * amz) + dte * cz;
            const float hn_t = qsum(ahn + dte * amn) + dte * cn;
            float r, z, n;
            if constexpr (GI) {
                r = sigmoid_f(sr_t + grf);
                z = sigmoid_f(sz_t + gzf);
                n = tanh_f(gnf + r * (hn_t + bhn_n));
            } else {
                r = sigmoid_f(sr_t + grf + brz_r);
                z = sigmoid_f(sz_t + gzf + brz_z);
                n = tanh_f(gnf + bin_n + r * (hn_t + bhn_n));
            }
            hnew  = (1.0f - z) * n + z * hode;
            hlast = hnew;
        } else {
            hnew = hode;
        }

        if (q == 0) sh_h[nxt][j] = (_Float16)hnew;
        hj = hnew;
        seen |= m;
        if constexpr (GI) { c_r = n_r; c_z = n_z; c_n = n_n; n_r = p_r; n_z = p_z; n_n = p_n; }
        else { xc0 = xn0; xc1 = xn1; xc2 = xn2; xc3 = xn3; }
        dtc = dt_n; mc = m_n;
        WAVEBAR();
    }

    // ---- epilogue (f32): out = W_out @ h_last + b_out ----
    if (q == 0) sh_eo[j] = hlast;
    __syncthreads();
    float ao = 0.0f;
#pragma unroll
    for (int i = 0; i < 8; ++i) {
        const int c = kb + (((i + 2 * q) & 7) << 2);
        const float4 wv = *(const float4*)(W_out + (size_t)j * NH + c);
        const float4 hv = *(const float4*)(sh_eo + c);
        ao += wv.x * hv.x + wv.y * hv.y + wv.z * hv.z + wv.w * hv.w;
    }
    ao = qsum(ao);
    if (q == 0) out[(size_t)b * NH + j] = ao + b_out[j];
}

extern "C" void kernel_launch(void* const* d_in, const int* in_sizes, int n_in,
                              void* d_out, int out_size, void* d_ws, size_t ws_size,
                              hipStream_t stream) {
    const float* x     = (const float*)d_in[0];
    const float* tps   = (const float*)d_in[1];
    const int*   mask  = (const int*)  d_in[2];
    const float* W_ih  = (const float*)d_in[3];
    const float* W_hh  = (const float*)d_in[4];
    const float* b_ih  = (const float*)d_in[5];
    const float* b_hh  = (const float*)d_in[6];
    const float* nW1   = (const float*)d_in[7];
    const float* nb1   = (const float*)d_in[8];
    const float* nW2   = (const float*)d_in[9];
    const float* nb2   = (const float*)d_in[10];
    const float* W_out = (const float*)d_in[11];
    const float* b_out = (const float*)d_in[12];
    float* out = (float*)d_out;

    const size_t M_BYTES  = (size_t)384 * NH * sizeof(float);          // 196,608
    const size_t GI_BYTES = (size_t)NT * NB * 384 * sizeof(ushort);    // 196,608,000
    float*  Mw  = (float*)d_ws;
    ushort* giu = (ushort*)((char*)d_ws + M_BYTES);

    mfuse<<<dim3(384), dim3(128), 0, stream>>>(W_hh, nW2, Mw);
    if (ws_size >= M_BYTES + GI_BYTES) {
        gi_pre<<<dim3(NB, 8), dim3(384), 0, stream>>>(x, W_ih, b_ih, b_hh, giu);
        gruode_scan<1><<<dim3(NB), dim3(512), 0, stream>>>(
            x, tps, mask, W_ih, W_hh, b_ih, b_hh,
            nW1, nb1, nW2, nb2, W_out, b_out, Mw, giu, out);
    } else {
        gruode_scan<0><<<dim3(NB), dim3(512), 0, stream>>>(
            x, tps, mask, W_ih, W_hh, b_ih, b_hh,
            nW1, nb1, nW2, nb2, W_out, b_out, Mw, nullptr, out);
    }
}

// Round 16
// 937.652 us; speedup vs baseline: 2.8856x; 1.1008x over previous
//
#include <hip/hip_runtime.h>

#define NB 256
#define NT 1000
#define ND 64
#define NH 128

typedef _Float16 h2 __attribute__((ext_vector_type(2)));

static __device__ __forceinline__ uint pk(float a, float b) {
    return __builtin_bit_cast(uint, __builtin_amdgcn_cvt_pkrtz(a, b));
}
static __device__ __forceinline__ float fdot2u(uint a, uint b, float c) {
#if __has_builtin(__builtin_amdgcn_fdot2)
    return __builtin_amdgcn_fdot2(__builtin_bit_cast(h2, a),
                                  __builtin_bit_cast(h2, b), c, false);
#else
    h2 ha = __builtin_bit_cast(h2, a), hb = __builtin_bit_cast(h2, b);
    return c + (float)ha.x * (float)hb.x + (float)ha.y * (float)hb.y;
#endif
}
static __device__ __forceinline__ float sigmoid_f(float x) {
    float e = __builtin_amdgcn_exp2f(-1.4426950408889634f * x);
    return __builtin_amdgcn_rcpf(1.0f + e);
}
static __device__ __forceinline__ float tanh_f(float x) {
    float e = __builtin_amdgcn_exp2f(-2.8853900817779268f * x);
    return 2.0f * __builtin_amdgcn_rcpf(1.0f + e) - 1.0f;
}
// quad butterfly sum via DPP
static __device__ __forceinline__ float qsum(float v) {
    int a = __builtin_amdgcn_update_dpp(0, __builtin_bit_cast(int, v),
                                        0xB1, 0xF, 0xF, true); // quad_perm(1,0,3,2)
    v += __builtin_bit_cast(float, a);
    int b = __builtin_amdgcn_update_dpp(0, __builtin_bit_cast(int, v),
                                        0x4E, 0xF, 0xF, true); // quad_perm(2,3,0,1)
    v += __builtin_bit_cast(float, b);
    return v;
}
// load 8 consecutive f32, pack to 4 f16x2 regs
static __device__ __forceinline__ void ld8(const float* p, uint* d) {
    const float4 A = *(const float4*)p;
    const float4 B = *(const float4*)(p + 4);
    d[0] = pk(A.x, A.y); d[1] = pk(A.z, A.w);
    d[2] = pk(B.x, B.y); d[3] = pk(B.z, B.w);
}
#define PIN(v) asm volatile("" : "+v"(v))
// raw barrier: orders LDS only; global prefetch loads stay in flight
#define WAVEBAR() asm volatile("s_waitcnt lgkmcnt(0)\n\ts_barrier" ::: "memory")

// ---------- gi precompute: giu[t][b][row] (f16) = W_ih@x + folded biases ----------
// row g*128+j gets +(b_ih+b_hh)[row] for g<2 (r,z gates); +b_ih[row] for g=2 (n gate).
// (verified rounds 14/15: absmax unchanged)
__global__ __launch_bounds__(384) void gi_pre(
    const float* __restrict__ x,      // (B,T,D)
    const float* __restrict__ W_ih,   // (384,64)
    const float* __restrict__ b_ih,   // (384)
    const float* __restrict__ b_hh,   // (384)
    ushort* __restrict__ giu)         // (T,B,384)
{
    __shared__ uint xt[125][32];      // f16-packed x tile (16 KB)
    const int tid = threadIdx.x;      // W_ih row
    const int b   = blockIdx.x;
    const int t0  = blockIdx.y * 125;

    uint wr[32];
    const float* wrow = W_ih + (size_t)tid * ND;
#pragma unroll
    for (int k = 0; k < 8; ++k) ld8(wrow + k * 8, wr + k * 4);
    const float badd = (tid < 256) ? (b_ih[tid] + b_hh[tid]) : b_ih[tid];

    for (int i = tid; i < 125 * 32; i += 384) {
        const int t = i >> 5, c = i & 31;
        const float2 v = *(const float2*)(x + ((size_t)b * NT + t0 + t) * ND + c * 2);
        xt[t][c] = pk(v.x, v.y);
    }
    __syncthreads();

    for (int t = 0; t < 125; ++t) {
        const uint4* xr = (const uint4*)&xt[t][0];   // broadcast reads
        float a0 = 0.0f, a1 = 0.0f;
#pragma unroll
        for (int k4 = 0; k4 < 8; ++k4) {
            const uint4 hv = xr[k4];
            a0 = fdot2u(wr[k4 * 4 + 0], hv.x, a0);
            a1 = fdot2u(wr[k4 * 4 + 1], hv.y, a1);
            a0 = fdot2u(wr[k4 * 4 + 2], hv.z, a0);
            a1 = fdot2u(wr[k4 * 4 + 3], hv.w, a1);
        }
        giu[((size_t)(t0 + t) * NB + b) * 384 + tid] =
            __builtin_bit_cast(ushort, (_Float16)(a0 + a1 + badd));
    }
}

// ---------- 3-phase scan (m==1) / 2-phase (m==0); 80-u32 fragment set ----------
template<int GI>
__global__
__attribute__((amdgpu_flat_work_group_size(512, 512)))
__attribute__((amdgpu_waves_per_eu(2, 2)))
void gruode_scan(
    const float* __restrict__ x,      // (B,T,D)  (GI=0 only)
    const float* __restrict__ tps,    // (T)
    const int*   __restrict__ mask,   // (B,T)
    const float* __restrict__ W_ih,   // (384,64)  (GI=0 only)
    const float* __restrict__ W_hh,   // (384,128)
    const float* __restrict__ b_ih,   // (384)
    const float* __restrict__ b_hh,   // (384)
    const float* __restrict__ nW1,    // (128,128)
    const float* __restrict__ nb1,    // (128)
    const float* __restrict__ nW2,    // (128,128)
    const float* __restrict__ nb2,    // (128)
    const float* __restrict__ W_out,  // (128,128)
    const float* __restrict__ b_out,  // (128)
    const ushort* __restrict__ giu,   // (T,B,384) f16, biases folded (GI=1)
    float* __restrict__ out)          // (B,128)
{
    __shared__ __align__(16) _Float16 sh_h[2][NH];
    __shared__ __align__(16) _Float16 sh_tmp[NH];
    __shared__ __align__(16) _Float16 sh_ode[NH];
    __shared__ float sh_eo[NH];
    __shared__ float sh_dt[NT];
    __shared__ int   sh_m[NT];

    const int tid = threadIdx.x;
    const int j   = tid >> 2;   // output row 0..127
    const int q   = tid & 3;    // K-quarter
    const int b   = blockIdx.x;
    const int kb  = q * 32;     // f16 col base
    const int qb  = q * 64;     // byte base within 128-f16 row

#define WSEL(i) (((i) + (q >> 1)) & 3)   // verified conflict-free rotation

    // ---- stage weights: 5 fragment sets = 80 u32 (fits 128-reg budget) ----
    uint w1[4][4], w2[4][4], whr[4][4], whz[4][4], whn[4][4];
#pragma unroll
    for (int i = 0; i < 4; ++i) {
        const int c = kb + (WSEL(i) << 3);
        ld8(nW1  + (size_t)(j      ) * NH + c, w1[i]);
        ld8(nW2  + (size_t)(j      ) * NH + c, w2[i]);
        ld8(W_hh + (size_t)(j      ) * NH + c, whr[i]);
        ld8(W_hh + (size_t)(j + 128) * NH + c, whz[i]);
        ld8(W_hh + (size_t)(j + 256) * NH + c, whn[i]);
    }
    uint wir[8], wiz[8], win[8];
    if constexpr (!GI) {
        const int kbi = q * 16;
        ld8(W_ih + (size_t)(j      ) * ND + kbi,     wir);
        ld8(W_ih + (size_t)(j      ) * ND + kbi + 8, wir + 4);
        ld8(W_ih + (size_t)(j + 128) * ND + kbi,     wiz);
        ld8(W_ih + (size_t)(j + 128) * ND + kbi + 8, wiz + 4);
        ld8(W_ih + (size_t)(j + 256) * ND + kbi,     win);
        ld8(W_ih + (size_t)(j + 256) * ND + kbi + 8, win + 4);
    }
    float bb1   = nb1[j];
    float bb2   = nb2[j];
    float brz_r = b_ih[j]       + b_hh[j];        // GI=0 path only
    float brz_z = b_ih[j + 128] + b_hh[j + 128];  // GI=0 path only
    float bin_n = b_ih[j + 256];                  // GI=0 path only
    float bhn_n = b_hh[j + 256];

#pragma unroll
    for (int i = 0; i < 4; ++i)
#pragma unroll
        for (int k = 0; k < 4; ++k) {
            PIN(w1[i][k]); PIN(w2[i][k]);
            PIN(whr[i][k]); PIN(whz[i][k]); PIN(whn[i][k]);
        }
    PIN(bb1); PIN(bb2); PIN(bhn_n);

    // ---- stage dt / mask; init h ----
    for (int s = tid; s < NT; s += 512) {
        sh_dt[s] = (s == 0) ? 0.0f : (tps[s] - tps[s - 1]);
        sh_m[s]  = mask[b * NT + s];
    }
    if (tid < NH) sh_h[0][tid] = (_Float16)0.0f;
    __syncthreads();

    float hj = 0.0f, hlast = 0.0f;
    int   seen = 0;

    // gi prefetch, 2 steps deep
    const size_t GSTR = (size_t)NB * 384;
    const ushort* gb = giu + (size_t)b * 384 + j;
    ushort c_r, c_z, c_n, n_r, n_z, n_n;
    const float* xbase = x + (size_t)b * NT * ND + q * 16;
    float4 xc0, xc1, xc2, xc3;
    if constexpr (GI) {
        c_r = gb[0];           c_z = gb[128];           c_n = gb[256];
        n_r = gb[GSTR];        n_z = gb[GSTR + 128];    n_n = gb[GSTR + 256];
    } else {
        xc0 = *(const float4*)(xbase);
        xc1 = *(const float4*)(xbase + 4);
        xc2 = *(const float4*)(xbase + 8);
        xc3 = *(const float4*)(xbase + 12);
    }
    float dtc = sh_dt[0];
    int   mc  = sh_m[0];

    for (int s = 0; s < NT; ++s) {
        const int cur = s & 1, nxt = cur ^ 1;

        // issue prefetches (stay in flight across raw barriers)
        ushort p_r, p_z, p_n;
        float4 xn0, xn1, xn2, xn3;
        if constexpr (GI) {
            const int sp = (s + 2 < NT) ? (s + 2) : (NT - 1);
            const ushort* g2 = gb + (size_t)sp * GSTR;
            p_r = g2[0]; p_z = g2[128]; p_n = g2[256];
        } else {
            const int sn_ = (s + 1 < NT) ? (s + 1) : s;
            const float* xr = xbase + (size_t)sn_ * ND;
            xn0 = *(const float4*)(xr);
            xn1 = *(const float4*)(xr + 4);
            xn2 = *(const float4*)(xr + 8);
            xn3 = *(const float4*)(xr + 12);
        }
        const int sn = (s + 1 < NT) ? (s + 1) : s;
        const float dt_n = sh_dt[sn];
        const int   m_n  = sh_m[sn];

        const int   m   = mc;                  // uniform per block
        const float dte = seen ? dtc : 0.0f;   // r_fill freeze

        // input-gate contributions (biases folded in giu for GI=1)
        float grf, gzf, gnf;
        if constexpr (GI) {
            grf = (float)__builtin_bit_cast(_Float16, c_r);
            gzf = (float)__builtin_bit_cast(_Float16, c_z);
            gnf = (float)__builtin_bit_cast(_Float16, c_n);
        } else {
            uint xh[8];
            xh[0] = pk(xc0.x, xc0.y); xh[1] = pk(xc0.z, xc0.w);
            xh[2] = pk(xc1.x, xc1.y); xh[3] = pk(xc1.z, xc1.w);
            xh[4] = pk(xc2.x, xc2.y); xh[5] = pk(xc2.z, xc2.w);
            xh[6] = pk(xc3.x, xc3.y); xh[7] = pk(xc3.z, xc3.w);
            grf = gzf = gnf = 0.0f;
            if (m) {
#pragma unroll
                for (int k = 0; k < 8; ++k) {
                    grf = fdot2u(wir[k], xh[k], grf);
                    gzf = fdot2u(wiz[k], xh[k], gzf);
                    gnf = fdot2u(win[k], xh[k], gnf);
                }
            }
        }

        // ---- phase A: a1 = W1 h ----
        float a1 = 0.0f;
        const char* hb = (const char*)&sh_h[cur][0];
#pragma unroll
        for (int i = 0; i < 4; ++i) {
            const uint4 hv = *(const uint4*)(hb + qb + WSEL(i) * 16);
            a1 = fdot2u(w1[i][0], hv.x, a1); a1 = fdot2u(w1[i][1], hv.y, a1);
            a1 = fdot2u(w1[i][2], hv.z, a1); a1 = fdot2u(w1[i][3], hv.w, a1);
        }
        const float a1q = qsum(a1);
        if (q == 0) sh_tmp[j] = (_Float16)tanh_f(a1q + bb1);
        WAVEBAR();

        // ---- phase B: a2 = W2 tmp -> h_ode ----
        float a2 = 0.0f;
#pragma unroll
        for (int i = 0; i < 4; ++i) {
            const uint4 tv = *(const uint4*)((const char*)sh_tmp + qb + WSEL(i) * 16);
            a2 = fdot2u(w2[i][0], tv.x, a2); a2 = fdot2u(w2[i][1], tv.y, a2);
            a2 = fdot2u(w2[i][2], tv.z, a2); a2 = fdot2u(w2[i][3], tv.w, a2);
        }
        const float a2q  = qsum(a2);
        const float hode = hj + dte * (a2q + bb2);

        float hnew;
        if (m) {
            // ---- phase C: AH = W_hh h_ode ; gates (m==1 only, block-uniform) ----
            if (q == 0) sh_ode[j] = (_Float16)hode;
            WAVEBAR();
            float ahr = 0.0f, ahz = 0.0f, ahn = 0.0f;
#pragma unroll
            for (int i = 0; i < 4; ++i) {
                const uint4 hv = *(const uint4*)((const char*)sh_ode + qb + WSEL(i) * 16);
                ahr = fdot2u(whr[i][0], hv.x, ahr); ahr = fdot2u(whr[i][1], hv.y, ahr);
                ahr = fdot2u(whr[i][2], hv.z, ahr); ahr = fdot2u(whr[i][3], hv.w, ahr);
                ahz = fdot2u(whz[i][0], hv.x, ahz); ahz = fdot2u(whz[i][1], hv.y, ahz);
                ahz = fdot2u(whz[i][2], hv.z, ahz); ahz = fdot2u(whz[i][3], hv.w, ahz);
                ahn = fdot2u(whn[i][0], hv.x, ahn); ahn = fdot2u(whn[i][1], hv.y, ahn);
                ahn = fdot2u(whn[i][2], hv.z, ahn); ahn = fdot2u(whn[i][3], hv.w, ahn);
            }
            const float sr_t = qsum(ahr);
            const float sz_t = qsum(ahz);
            const float hn_t = qsum(ahn);
            float r, z, n;
            if constexpr (GI) {
                r = sigmoid_f(sr_t + grf);
                z = sigmoid_f(sz_t + gzf);
                n = tanh_f(gnf + r * (hn_t + bhn_n));
            } else {
                r = sigmoid_f(sr_t + grf + brz_r);
                z = sigmoid_f(sz_t + gzf + brz_z);
                n = tanh_f(gnf + bin_n + r * (hn_t + bhn_n));
            }
            hnew  = (1.0f - z) * n + z * hode;
            hlast = hnew;
        } else {
            hnew = hode;
        }

        if (q == 0) sh_h[nxt][j] = (_Float16)hnew;
        hj = hnew;
        seen |= m;
        if constexpr (GI) { c_r = n_r; c_z = n_z; c_n = n_n; n_r = p_r; n_z = p_z; n_n = p_n; }
        else { xc0 = xn0; xc1 = xn1; xc2 = xn2; xc3 = xn3; }
        dtc = dt_n; mc = m_n;
        WAVEBAR();
    }

    // ---- epilogue (f32): out = W_out @ h_last + b_out ----
    if (q == 0) sh_eo[j] = hlast;
    __syncthreads();
    float ao = 0.0f;
#pragma unroll
    for (int i = 0; i < 8; ++i) {
        const int c = kb + (((i + 2 * q) & 7) << 2);
        const float4 wv = *(const float4*)(W_out + (size_t)j * NH + c);
        const float4 hv = *(const float4*)(sh_eo + c);
        ao += wv.x * hv.x + wv.y * hv.y + wv.z * hv.z + wv.w * hv.w;
    }
    ao = qsum(ao);
    if (q == 0) out[(size_t)b * NH + j] = ao + b_out[j];
}

extern "C" void kernel_launch(void* const* d_in, const int* in_sizes, int n_in,
                              void* d_out, int out_size, void* d_ws, size_t ws_size,
                              hipStream_t stream) {
    const float* x     = (const float*)d_in[0];
    const float* tps   = (const float*)d_in[1];
    const int*   mask  = (const int*)  d_in[2];
    const float* W_ih  = (const float*)d_in[3];
    const float* W_hh  = (const float*)d_in[4];
    const float* b_ih  = (const float*)d_in[5];
    const float* b_hh  = (const float*)d_in[6];
    const float* nW1   = (const float*)d_in[7];
    const float* nb1   = (const float*)d_in[8];
    const float* nW2   = (const float*)d_in[9];
    const float* nb2   = (const float*)d_in[10];
    const float* W_out = (const float*)d_in[11];
    const float* b_out = (const float*)d_in[12];
    float* out = (float*)d_out;

    const size_t GI_BYTES = (size_t)NT * NB * 384 * sizeof(ushort);    // 196,608,000
    ushort* giu = (ushort*)d_ws;

    if (ws_size >= GI_BYTES) {
        gi_pre<<<dim3(NB, 8), dim3(384), 0, stream>>>(x, W_ih, b_ih, b_hh, giu);
        gruode_scan<1><<<dim3(NB), dim3(512), 0, stream>>>(
            x, tps, mask, W_ih, W_hh, b_ih, b_hh,
            nW1, nb1, nW2, nb2, W_out, b_out, giu, out);
    } else {
        gruode_scan<0><<<dim3(NB), dim3(512), 0, stream>>>(
            x, tps, mask, W_ih, W_hh, b_ih, b_hh,
            nW1, nb1, nW2, nb2, W_out, b_out, nullptr, out);
    }
}